// Round 1
// baseline (406.201 us; speedup 1.0000x reference)
//
#include <hip/hip_runtime.h>
#include <cmath>

typedef unsigned int u32;
typedef unsigned long long u64;
typedef unsigned char u8;

// Marching-tets tables from the reference
__constant__ signed char c_tri[16][6] = {
    {-1,-1,-1,-1,-1,-1},
    { 1, 0, 2,-1,-1,-1},
    { 4, 0, 3,-1,-1,-1},
    { 1, 4, 2, 1, 3, 4},
    { 3, 1, 5,-1,-1,-1},
    { 2, 3, 0, 2, 5, 3},
    { 1, 4, 0, 1, 5, 4},
    { 4, 2, 5,-1,-1,-1},
    { 4, 5, 2,-1,-1,-1},
    { 4, 1, 0, 4, 5, 1},
    { 3, 2, 0, 3, 5, 2},
    { 1, 3, 5,-1,-1,-1},
    { 4, 1, 2, 4, 3, 1},
    { 3, 0, 4,-1,-1,-1},
    { 2, 0, 1,-1,-1,-1},
    {-1,-1,-1,-1,-1,-1}};
__constant__ signed char c_ntri[16] = {0,1,1,2,1,2,2,1,1,2,2,1,2,1,1,0};
__constant__ signed char c_edge_p[6] = {0,0,0,1,1,2};
__constant__ signed char c_edge_q[6] = {1,2,3,2,3,3};

// ---------------- Stage V1: per-vertex crossing mask + per-block counts ----
__global__ void k_vmask(const float* __restrict__ sdf, u8* __restrict__ vmask,
                        u32* __restrict__ vbsums, int Nv, int V) {
    int v = blockIdx.x * 256 + threadIdx.x;
    u32 cnt = 0;
    if (v < Nv) {
        int x = v % V;
        int t = v / V;
        int y = t % V;
        int z = t / V;
        const int V2 = V * V;
        bool occ0 = sdf[v] > 0.0f;
        bool bx = x < V - 1, by = y < V - 1, bz = z < V - 1;
        int  d[7]  = {1, V, V + 1, V2, V2 + 1, V2 + V, V2 + V + 1};
        bool ok[7] = {bx, by, bx && by, bz, bx && bz, by && bz, bx && by && bz};
        u32 m = 0;
#pragma unroll
        for (int k = 0; k < 7; ++k) {
            if (ok[k]) {
                bool occ1 = sdf[v + d[k]] > 0.0f;
                if (occ1 != occ0) m |= (1u << k);
            }
        }
        vmask[v] = (u8)m;
        cnt = __popc(m);
    }
    __shared__ u32 sh[256];
    sh[threadIdx.x] = cnt;
    __syncthreads();
    for (int off = 128; off > 0; off >>= 1) {
        if ((int)threadIdx.x < off) sh[threadIdx.x] += sh[threadIdx.x + off];
        __syncthreads();
    }
    if (threadIdx.x == 0) vbsums[blockIdx.x] = sh[0];
}

// ---------------- Generic single-block exclusive scan (u32, in place) ------
__global__ void k_scan_u32(u32* __restrict__ data, int n, u32* __restrict__ totalp) {
    __shared__ u32 sh[1024];
    __shared__ u32 carry;
    if (threadIdx.x == 0) carry = 0;
    __syncthreads();
    for (int start = 0; start < n; start += 1024) {
        int i = start + (int)threadIdx.x;
        u32 v = (i < n) ? data[i] : 0u;
        u32 c = carry;
        __syncthreads();
        sh[threadIdx.x] = v;
        __syncthreads();
        for (int o = 1; o < 1024; o <<= 1) {
            u32 t = ((int)threadIdx.x >= o) ? sh[threadIdx.x - o] : 0u;
            __syncthreads();
            sh[threadIdx.x] += t;
            __syncthreads();
        }
        if (i < n) data[i] = c + sh[threadIdx.x] - v;
        __syncthreads();
        if (threadIdx.x == 0) carry = c + sh[1023];
        __syncthreads();
    }
    if (threadIdx.x == 0) totalp[0] = carry;  // E
}

// ---------------- Stage V3: per-vertex exclusive base -----------------------
__global__ void k_vbase(const u8* __restrict__ vmask, const u32* __restrict__ vbsums,
                        u32* __restrict__ vbase, int Nv) {
    int v = blockIdx.x * 256 + threadIdx.x;
    u32 cnt = (v < Nv) ? (u32)__popc((u32)vmask[v]) : 0u;
    __shared__ u32 sh[256];
    sh[threadIdx.x] = cnt;
    __syncthreads();
    for (int o = 1; o < 256; o <<= 1) {
        u32 t = ((int)threadIdx.x >= o) ? sh[threadIdx.x - o] : 0u;
        __syncthreads();
        sh[threadIdx.x] += t;
        __syncthreads();
    }
    if (v < Nv) vbase[v] = vbsums[blockIdx.x] + sh[threadIdx.x] - cnt;
}

// ---------------- Stage T1: classify tets, per-block (m1,m2) sums ----------
__global__ void k_tet1(const int* __restrict__ tet, const float* __restrict__ sdf,
                       u8* __restrict__ tcode, u32* __restrict__ tbs, int F) {
    int t = blockIdx.x * 256 + threadIdx.x;
    int nt = 0;
    if (t < F) {
        long long b4 = 4ll * t;
        int a = tet[b4], b = tet[b4 + 1], c = tet[b4 + 2], d = tet[b4 + 3];
        int ti = (int)(sdf[a] > 0.0f) | ((int)(sdf[b] > 0.0f) << 1) |
                 ((int)(sdf[c] > 0.0f) << 2) | ((int)(sdf[d] > 0.0f) << 3);
        tcode[t] = (u8)ti;
        nt = c_ntri[ti];
    }
    u32 pair = (nt == 1 ? 1u : 0u) | (nt == 2 ? (1u << 16) : 0u);
    __shared__ u32 sh[256];
    sh[threadIdx.x] = pair;
    __syncthreads();
    for (int off = 128; off > 0; off >>= 1) {
        if ((int)threadIdx.x < off) sh[threadIdx.x] += sh[threadIdx.x + off];
        __syncthreads();
    }
    if (threadIdx.x == 0) tbs[blockIdx.x] = sh[0];
}

// ---------------- Stage T2: scan packed (m1,m2) block sums -----------------
__global__ void k_scan_tet(const u32* __restrict__ tbs, uint2* __restrict__ toffs,
                           int n, u32* __restrict__ totals) {
    __shared__ u64 sh[1024];
    __shared__ u64 carry;
    if (threadIdx.x == 0) carry = 0;
    __syncthreads();
    for (int start = 0; start < n; start += 1024) {
        int i = start + (int)threadIdx.x;
        u32 raw = (i < n) ? tbs[i] : 0u;
        u64 v = (u64)(raw & 0xFFFFu) | ((u64)(raw >> 16) << 32);
        u64 c = carry;
        __syncthreads();
        sh[threadIdx.x] = v;
        __syncthreads();
        for (int o = 1; o < 1024; o <<= 1) {
            u64 t = ((int)threadIdx.x >= o) ? sh[threadIdx.x - o] : 0ull;
            __syncthreads();
            sh[threadIdx.x] += t;
            __syncthreads();
        }
        if (i < n) {
            u64 e = c + sh[threadIdx.x] - v;
            toffs[i] = make_uint2((u32)(e & 0xFFFFFFFFull), (u32)(e >> 32));
        }
        __syncthreads();
        if (threadIdx.x == 0) carry = c + sh[1023];
        __syncthreads();
    }
    if (threadIdx.x == 0) {
        totals[1] = (u32)(carry & 0xFFFFFFFFull);  // Tm1
        totals[2] = (u32)(carry >> 32);            // Tm2
    }
}

// ---------------- verts: interpolate crossing edges ------------------------
__global__ void k_verts(const float* __restrict__ pos, const float* __restrict__ sdf,
                        const u8* __restrict__ vmask, const u32* __restrict__ vbase,
                        float* __restrict__ out, int Nv, int V) {
    int v = blockIdx.x * 256 + threadIdx.x;
    if (v >= Nv) return;
    u32 m = vmask[v];
    if (!m) return;
    const int V2 = V * V;
    const int d[7] = {1, V, V + 1, V2, V2 + 1, V2 + V, V2 + V + 1};
    float s0 = sdf[v];
    float p0x = pos[3ll * v], p0y = pos[3ll * v + 1], p0z = pos[3ll * v + 2];
    u32 r = vbase[v];
#pragma unroll
    for (int k = 0; k < 7; ++k) {
        if (m & (1u << k)) {
            int n = v + d[k];
            float s1 = sdf[n];
            float denom = s0 - s1;
            float w0 = -s1 / denom;
            float w1 = s0 / denom;
            out[3ull * r + 0] = p0x * w0 + pos[3ll * n + 0] * w1;
            out[3ull * r + 1] = p0y * w0 + pos[3ll * n + 1] * w1;
            out[3ull * r + 2] = p0z * w0 + pos[3ll * n + 2] * w1;
            r++;
        }
    }
}

// ---------------- faces + uv_idx -------------------------------------------
__global__ void k_faces(const int* __restrict__ tet, const u8* __restrict__ tcode,
                        const uint2* __restrict__ toffs,
                        const u8* __restrict__ vmask, const u32* __restrict__ vbase,
                        const u32* __restrict__ totals,
                        float* __restrict__ out, int F, int V, long long uvelems) {
    int t = blockIdx.x * 256 + threadIdx.x;
    int ti = (t < F) ? (int)tcode[t] : 0;
    int nt = c_ntri[ti];
    u32 pair = (nt == 1 ? 1u : 0u) | (nt == 2 ? (1u << 16) : 0u);
    __shared__ u32 sh[256];
    sh[threadIdx.x] = pair;
    __syncthreads();
    for (int o = 1; o < 256; o <<= 1) {
        u32 x = ((int)threadIdx.x >= o) ? sh[threadIdx.x - o] : 0u;
        __syncthreads();
        sh[threadIdx.x] += x;
        __syncthreads();
    }
    u32 excl = sh[threadIdx.x] - pair;
    if (t >= F || nt == 0) return;

    uint2 bo = toffs[blockIdx.x];
    u32 m1pos = bo.x + (excl & 0xFFFFu);
    u32 m2pos = bo.y + (excl >> 16);
    u32 E = totals[0], Tm1 = totals[1], Tm2 = totals[2];
    u64 T = (u64)Tm1 + 2ull * (u64)Tm2;
    float* faces = out + 3ull * E;
    float* uvidx = out + 3ull * E + 3ull * T + (u64)uvelems;

    long long b4 = 4ll * t;
    int tv0 = tet[b4], tv1 = tet[b4 + 1], tv2 = tet[b4 + 2], tv3 = tet[b4 + 3];
    int tv[4] = {tv0, tv1, tv2, tv3};
    const int V2 = V * V;

    for (int tri = 0; tri < nt; ++tri) {
        u64 r = (nt == 1) ? (u64)m1pos : ((u64)Tm1 + 2ull * (u64)m2pos + (u64)tri);
#pragma unroll
        for (int cidx = 0; cidx < 3; ++cidx) {
            int e = c_tri[ti][3 * tri + cidx];
            int a = tv[(int)c_edge_p[e]];
            int b = tv[(int)c_edge_q[e]];
            int lo = a < b ? a : b;
            int hi = a < b ? b : a;
            int delta = hi - lo;
            int k;
            if (delta == 1) k = 0;
            else if (delta == V) k = 1;
            else if (delta == V + 1) k = 2;
            else if (delta == V2) k = 3;
            else if (delta == V2 + 1) k = 4;
            else if (delta == V2 + V) k = 5;
            else k = 6;
            u32 vi = vbase[lo] + (u32)__popc((u32)vmask[lo] & ((1u << k) - 1u));
            faces[3ull * r + cidx] = (float)vi;
        }
        uvidx[3ull * r + 0] = (float)(4ll * t);
        uvidx[3ull * r + 1] = (float)(4ll * t + tri + 1);
        uvidx[3ull * r + 2] = (float)(4ll * t + tri + 2);
    }
}

// ---------------- uvs: static texture-coordinate grid ----------------------
__global__ void k_uvs(float* __restrict__ out, const u32* __restrict__ totals,
                      int Nuv, int npts) {
    int idx = blockIdx.x * 256 + threadIdx.x;
    if (idx >= npts) return;
    u32 E = totals[0], Tm1 = totals[1], Tm2 = totals[2];
    u64 T = (u64)Tm1 + 2ull * (u64)Tm2;
    float* uvs = out + 3ull * E + 3ull * T;
    int q = idx >> 2, c = idx & 3;
    int i = q / Nuv;
    int j = q - i * Nuv;
    double step = (1.0 - 1.0 / (double)Nuv) / (double)(Nuv - 1);
    float tx = (j == Nuv - 1) ? (float)(1.0 - 1.0 / (double)Nuv) : (float)((double)j * step);
    float ty = (i == Nuv - 1) ? (float)(1.0 - 1.0 / (double)Nuv) : (float)((double)i * step);
    float pad = (float)(0.9 / (double)Nuv);
    float u = (c == 1 || c == 2) ? tx + pad : tx;
    float w = (c >= 2) ? ty + pad : ty;
    uvs[2ull * idx + 0] = u;
    uvs[2ull * idx + 1] = w;
}

extern "C" void kernel_launch(void* const* d_in, const int* in_sizes, int n_in,
                              void* d_out, int out_size, void* d_ws, size_t ws_size,
                              hipStream_t stream) {
    const float* pos = (const float*)d_in[0];
    const float* sdf = (const float*)d_in[1];
    const int* tet = (const int*)d_in[2];
    int Nv = in_sizes[1];
    int F = in_sizes[2] / 4;

    int V = 1;
    while ((long long)V * V * V < (long long)Nv) V++;

    long long half = (2ll * (long long)F + 1) / 2;
    int Nuv = (int)std::sqrt((double)half);
    while ((long long)Nuv * Nuv < half) Nuv++;
    while (Nuv > 1 && (long long)(Nuv - 1) * (Nuv - 1) >= half) Nuv--;

    int nbV = (Nv + 255) / 256;
    int nbT = (F + 255) / 256;
    int npts = 4 * Nuv * Nuv;            // 50,353,216 < 2^31
    long long uvelems = 2ll * npts;

    char* ws = (char*)d_ws;
    size_t off = 0;
    auto walloc = [&](size_t bytes) -> void* {
        void* p = ws + off;
        off = (off + bytes + 255) & ~(size_t)255;
        return p;
    };
    u32*   totals = (u32*)walloc(64);
    u32*   vbsums = (u32*)walloc(sizeof(u32) * (size_t)nbV);
    u32*   tbs    = (u32*)walloc(sizeof(u32) * (size_t)nbT);
    uint2* toffs  = (uint2*)walloc(sizeof(uint2) * (size_t)nbT);
    u8*    vmask  = (u8*)walloc((size_t)Nv);
    u32*   vbase  = (u32*)walloc(sizeof(u32) * (size_t)Nv);
    u8*    tcode  = (u8*)walloc((size_t)F);
    (void)ws_size;

    float* out = (float*)d_out;

    hipLaunchKernelGGL(k_vmask, dim3(nbV), dim3(256), 0, stream, sdf, vmask, vbsums, Nv, V);
    hipLaunchKernelGGL(k_scan_u32, dim3(1), dim3(1024), 0, stream, vbsums, nbV, totals);
    hipLaunchKernelGGL(k_vbase, dim3(nbV), dim3(256), 0, stream, vmask, vbsums, vbase, Nv);
    hipLaunchKernelGGL(k_tet1, dim3(nbT), dim3(256), 0, stream, tet, sdf, tcode, tbs, F);
    hipLaunchKernelGGL(k_scan_tet, dim3(1), dim3(1024), 0, stream, tbs, toffs, nbT, totals);
    hipLaunchKernelGGL(k_verts, dim3(nbV), dim3(256), 0, stream, pos, sdf, vmask, vbase, out, Nv, V);
    hipLaunchKernelGGL(k_faces, dim3(nbT), dim3(256), 0, stream, tet, tcode, toffs, vmask, vbase,
                       totals, out, F, V, uvelems);
    hipLaunchKernelGGL(k_uvs, dim3((npts + 255) / 256), dim3(256), 0, stream, out, totals, Nuv, npts);
}

// Round 2
// 287.830 us; speedup vs baseline: 1.4113x; 1.4113x over previous
//
#include <hip/hip_runtime.h>
#include <cmath>

typedef unsigned int u32;
typedef unsigned long long u64;
typedef unsigned char u8;

// Marching-tets tables from the reference
__constant__ signed char c_tri[16][6] = {
    {-1,-1,-1,-1,-1,-1},
    { 1, 0, 2,-1,-1,-1},
    { 4, 0, 3,-1,-1,-1},
    { 1, 4, 2, 1, 3, 4},
    { 3, 1, 5,-1,-1,-1},
    { 2, 3, 0, 2, 5, 3},
    { 1, 4, 0, 1, 5, 4},
    { 4, 2, 5,-1,-1,-1},
    { 4, 5, 2,-1,-1,-1},
    { 4, 1, 0, 4, 5, 1},
    { 3, 2, 0, 3, 5, 2},
    { 1, 3, 5,-1,-1,-1},
    { 4, 1, 2, 4, 3, 1},
    { 3, 0, 4,-1,-1,-1},
    { 2, 0, 1,-1,-1,-1},
    {-1,-1,-1,-1,-1,-1}};
__constant__ signed char c_ntri[16] = {0,1,1,2,1,2,2,1,1,2,2,1,2,1,1,0};
__constant__ signed char c_edge_p[6] = {0,0,0,1,1,2};
__constant__ signed char c_edge_q[6] = {1,2,3,2,3,3};
// 6-tet decomposition of a cube around the 0-7 diagonal (corner n: bit0=dx,bit1=dy,bit2=dz)
__constant__ u8 c_six[6][4] = {{0,5,1,7},{0,1,3,7},{0,3,2,7},{0,2,6,7},{0,6,4,7},{0,4,5,7}};

// ---- V-pass 1: crossing mask (bits 0..6) + occ (bit 7) + per-block counts --
__global__ void k_vmask(const float* __restrict__ sdf, u8* __restrict__ vmask,
                        u32* __restrict__ vbsums, int Nv, int V) {
    int v = blockIdx.x * 256 + threadIdx.x;
    u32 cnt = 0;
    if (v < Nv) {
        int x = v % V;
        int t = v / V;
        int y = t % V;
        int z = t / V;
        const int V2 = V * V;
        bool occ0 = sdf[v] > 0.0f;
        bool bx = x < V - 1, by = y < V - 1, bz = z < V - 1;
        int  d[7]  = {1, V, V + 1, V2, V2 + 1, V2 + V, V2 + V + 1};
        bool ok[7] = {bx, by, bx && by, bz, bx && bz, by && bz, bx && by && bz};
        u32 m = 0;
#pragma unroll
        for (int k = 0; k < 7; ++k) {
            if (ok[k]) {
                bool occ1 = sdf[v + d[k]] > 0.0f;
                if (occ1 != occ0) m |= (1u << k);
            }
        }
        vmask[v] = (u8)(m | (occ0 ? 0x80u : 0u));
        cnt = __popc(m);
    }
    // wave reduce then block reduce
    int lane = threadIdx.x & 63, wid = threadIdx.x >> 6;
    u32 s = cnt;
#pragma unroll
    for (int o = 32; o > 0; o >>= 1) s += __shfl_down(s, o, 64);
    __shared__ u32 wsum[4];
    if (lane == 0) wsum[wid] = s;
    __syncthreads();
    if (threadIdx.x == 0) vbsums[blockIdx.x] = wsum[0] + wsum[1] + wsum[2] + wsum[3];
}

// ---- C-pass 1: per-cube (m1,m2) tet counts, per-block packed sums ----------
__global__ void k_cubecnt(const u8* __restrict__ vmask, u32* __restrict__ cbsums,
                          int nC, int G, int V) {
    int ci = blockIdx.x * 256 + threadIdx.x;
    u32 pack = 0;
    if (ci < nC) {
        int x = ci % G;
        int t = ci / G;
        int y = t % G;
        int z = t / G;
        const int V2 = V * V;
        int nb = z * V2 + y * V + x;
        const int off[8] = {0, 1, V, V + 1, V2, V2 + 1, V2 + V, V2 + V + 1};
        u32 occ8 = 0;
#pragma unroll
        for (int n = 0; n < 8; ++n) occ8 |= (u32)(vmask[nb + off[n]] >> 7) << n;
        u32 c1 = 0, c2 = 0;
#pragma unroll
        for (int w = 0; w < 6; ++w) {
            int ti = ((occ8 >> c_six[w][0]) & 1) | (((occ8 >> c_six[w][1]) & 1) << 1) |
                     (((occ8 >> c_six[w][2]) & 1) << 2) | (((occ8 >> c_six[w][3]) & 1) << 3);
            int nt = c_ntri[ti];
            c1 += (nt == 1);
            c2 += (nt == 2);
        }
        pack = c1 | (c2 << 16);
    }
    int lane = threadIdx.x & 63, wid = threadIdx.x >> 6;
    u32 s = pack;
#pragma unroll
    for (int o = 32; o > 0; o >>= 1) s += __shfl_down(s, o, 64);
    __shared__ u32 wsum[4];
    if (lane == 0) wsum[wid] = s;
    __syncthreads();
    if (threadIdx.x == 0) cbsums[blockIdx.x] = wsum[0] + wsum[1] + wsum[2] + wsum[3];
}

// ---- scans (block 0: u32 vbsums; block 1: packed->u64 cbsums->coffs) -------
__global__ void k_scan_both(u32* __restrict__ vbsums, int nV,
                            const u32* __restrict__ cbsums, u64* __restrict__ coffs,
                            int nC, u32* __restrict__ totals) {
    int tid = threadIdx.x;
    int lane = tid & 63, wid = tid >> 6;
    if (blockIdx.x == 0) {
        __shared__ u32 wsum[16];
        __shared__ u32 carry;
        if (tid == 0) carry = 0;
        __syncthreads();
        for (int start = 0; start < nV; start += 1024) {
            int i = start + tid;
            u32 orig = (i < nV) ? vbsums[i] : 0u;
            u32 v = orig;
#pragma unroll
            for (int o = 1; o < 64; o <<= 1) {
                u32 t = __shfl_up(v, o, 64);
                if (lane >= o) v += t;
            }
            if (lane == 63) wsum[wid] = v;
            __syncthreads();
            if (wid == 0) {
                u32 w = (lane < 16) ? wsum[lane] : 0u;
#pragma unroll
                for (int o = 1; o < 16; o <<= 1) {
                    u32 t = __shfl_up(w, o, 64);
                    if (lane >= o) w += t;
                }
                if (lane < 16) wsum[lane] = w;
            }
            __syncthreads();
            u32 base = carry + (wid ? wsum[wid - 1] : 0u);
            if (i < nV) vbsums[i] = base + v - orig;
            __syncthreads();
            if (tid == 0) carry += wsum[15];
            __syncthreads();
        }
        if (tid == 0) totals[0] = carry;  // E
    } else {
        __shared__ u64 wsum[16];
        __shared__ u64 carry;
        if (tid == 0) carry = 0;
        __syncthreads();
        for (int start = 0; start < nC; start += 1024) {
            int i = start + tid;
            u32 raw = (i < nC) ? cbsums[i] : 0u;
            u64 orig = (u64)(raw & 0xFFFFu) | ((u64)(raw >> 16) << 32);
            u64 v = orig;
#pragma unroll
            for (int o = 1; o < 64; o <<= 1) {
                u64 t = __shfl_up(v, o, 64);
                if (lane >= o) v += t;
            }
            if (lane == 63) wsum[wid] = v;
            __syncthreads();
            if (wid == 0) {
                u64 w = (lane < 16) ? wsum[lane] : 0ull;
#pragma unroll
                for (int o = 1; o < 16; o <<= 1) {
                    u64 t = __shfl_up(w, o, 64);
                    if (lane >= o) w += t;
                }
                if (lane < 16) wsum[lane] = w;
            }
            __syncthreads();
            u64 base = carry + (wid ? wsum[wid - 1] : 0ull);
            if (i < nC) coffs[i] = base + v - orig;
            __syncthreads();
            if (tid == 0) carry += wsum[15];
            __syncthreads();
        }
        if (tid == 0) {
            totals[1] = (u32)(carry & 0xFFFFFFFFull);  // Tm1
            totals[2] = (u32)(carry >> 32);            // Tm2
        }
    }
}

// ---- vbase materialize + crossing-vertex interpolation (fused) ------------
__global__ void k_vbase_verts(const u8* __restrict__ vmask, const u32* __restrict__ vbsums,
                              u32* __restrict__ vbase, const float* __restrict__ sdf,
                              float* __restrict__ out, int Nv, int V, float h) {
    int v = blockIdx.x * 256 + threadIdx.x;
    u32 m = (v < Nv) ? (u32)(vmask[v] & 0x7Fu) : 0u;
    u32 cnt = __popc(m);
    int lane = threadIdx.x & 63, wid = threadIdx.x >> 6;
    u32 s = cnt;
#pragma unroll
    for (int o = 1; o < 64; o <<= 1) {
        u32 t = __shfl_up(s, o, 64);
        if (lane >= o) s += t;
    }
    __shared__ u32 wsum[4];
    if (lane == 63) wsum[wid] = s;
    __syncthreads();
    u32 wb = 0;
    for (int k = 0; k < 4; ++k)
        if (k < wid) wb += wsum[k];
    u32 base = vbsums[blockIdx.x] + wb + s - cnt;
    if (v < Nv) vbase[v] = base;
    if (!m) return;

    int x = v % V;
    int t2 = v / V;
    int y = t2 % V;
    int z = t2 / V;
    const int V2 = V * V;
    const int d[7]  = {1, V, V + 1, V2, V2 + 1, V2 + V, V2 + V + 1};
    const int dx[7] = {1, 0, 1, 0, 1, 0, 1};
    const int dy[7] = {0, 1, 1, 0, 0, 1, 1};
    const int dz[7] = {0, 0, 0, 1, 1, 1, 1};
    float px = -1.0f + x * h, py = -1.0f + y * h, pz = -1.0f + z * h;
    float s0 = sdf[v];
    u32 r = base;
#pragma unroll
    for (int k = 0; k < 7; ++k) {
        if (m & (1u << k)) {
            float s1 = sdf[v + d[k]];
            float denom = s0 - s1;
            float w0 = -s1 / denom;
            float w1 = s0 / denom;
            out[3ull * r + 0] = px * w0 + (px + dx[k] * h) * w1;
            out[3ull * r + 1] = py * w0 + (py + dy[k] * h) * w1;
            out[3ull * r + 2] = pz * w0 + (pz + dz[k] * h) * w1;
            r++;
        }
    }
}

// ---- faces + uv_idx, per-cube, procedural connectivity --------------------
__global__ void k_facesuv(const u8* __restrict__ vmask, const u32* __restrict__ vbase,
                          const u64* __restrict__ coffs, const u32* __restrict__ totals,
                          float* __restrict__ out, int nC, int G, int V, long long npts2) {
    int ci = blockIdx.x * 256 + threadIdx.x;
    const int V2 = V * V;
    u32 pack = 0, occ8 = 0;
    int nb = 0;
    if (ci < nC) {
        int x = ci % G;
        int t = ci / G;
        int y = t % G;
        int z = t / G;
        nb = z * V2 + y * V + x;
        const int off[8] = {0, 1, V, V + 1, V2, V2 + 1, V2 + V, V2 + V + 1};
#pragma unroll
        for (int n = 0; n < 8; ++n) occ8 |= (u32)(vmask[nb + off[n]] >> 7) << n;
        u32 c1 = 0, c2 = 0;
#pragma unroll
        for (int w = 0; w < 6; ++w) {
            int ti = ((occ8 >> c_six[w][0]) & 1) | (((occ8 >> c_six[w][1]) & 1) << 1) |
                     (((occ8 >> c_six[w][2]) & 1) << 2) | (((occ8 >> c_six[w][3]) & 1) << 3);
            int nt = c_ntri[ti];
            c1 += (nt == 1);
            c2 += (nt == 2);
        }
        pack = c1 | (c2 << 16);
    }
    int lane = threadIdx.x & 63, wid = threadIdx.x >> 6;
    u32 s = pack;
#pragma unroll
    for (int o = 1; o < 64; o <<= 1) {
        u32 t = __shfl_up(s, o, 64);
        if (lane >= o) s += t;
    }
    __shared__ u32 wsum[4];
    if (lane == 63) wsum[wid] = s;
    __syncthreads();
    u32 wb = 0;
    for (int k = 0; k < 4; ++k)
        if (k < wid) wb += wsum[k];
    u32 excl = wb + s - pack;
    if (ci >= nC || pack == 0) return;

    u64 bo = coffs[blockIdx.x];
    u32 m1pos = (u32)(bo & 0xFFFFFFFFull) + (excl & 0xFFFFu);
    u32 m2pos = (u32)(bo >> 32) + (excl >> 16);
    u32 E = totals[0], Tm1 = totals[1], Tm2 = totals[2];
    u64 T = (u64)Tm1 + 2ull * (u64)Tm2;
    float* faces = out + 3ull * E;
    float* uvidx = out + 3ull * E + 3ull * T + (u64)npts2;
    const int off[8] = {0, 1, V, V + 1, V2, V2 + 1, V2 + V, V2 + V + 1};

#pragma unroll
    for (int w = 0; w < 6; ++w) {
        int ti = ((occ8 >> c_six[w][0]) & 1) | (((occ8 >> c_six[w][1]) & 1) << 1) |
                 (((occ8 >> c_six[w][2]) & 1) << 2) | (((occ8 >> c_six[w][3]) & 1) << 3);
        int nt = c_ntri[ti];
        if (!nt) continue;
        int t = ci * 6 + w;
        for (int tri = 0; tri < nt; ++tri) {
            u64 r = (nt == 1) ? (u64)m1pos : ((u64)Tm1 + 2ull * (u64)m2pos + (u64)tri);
#pragma unroll
            for (int cidx = 0; cidx < 3; ++cidx) {
                int e = c_tri[ti][3 * tri + cidx];
                int np_ = c_six[w][(int)c_edge_p[e]];
                int nq_ = c_six[w][(int)c_edge_q[e]];
                int lo = np_ < nq_ ? np_ : nq_;
                int k = (np_ ^ nq_) - 1;  // corners form a bit-subset chain
                int lonode = nb + off[lo];
                u32 vi = vbase[lonode] +
                         (u32)__popc((u32)(vmask[lonode] & 0x7Fu) & ((1u << k) - 1u));
                faces[3ull * r + cidx] = (float)vi;
            }
            uvidx[3ull * r + 0] = (float)(4 * t);
            uvidx[3ull * r + 1] = (float)(4 * t + tri + 1);
            uvidx[3ull * r + 2] = (float)(4 * t + tri + 2);
        }
        if (nt == 1) m1pos++;
        else m2pos++;
    }
}

// ---- uvs: static texture grid, 2D launch, no integer division -------------
__global__ void k_uvs(float* __restrict__ out, const u32* __restrict__ totals,
                      int Nuv, int rowElems) {
    int i = blockIdx.y;
    int e = blockIdx.x * 256 + threadIdx.x;
    if (e >= rowElems) return;
    u32 E = totals[0], Tm1 = totals[1], Tm2 = totals[2];
    u64 T = (u64)Tm1 + 2ull * (u64)Tm2;
    float* uvs = out + 3ull * E + 3ull * T;
    int j = e >> 3;
    int c = (e >> 1) & 3;
    double step = (1.0 - 1.0 / (double)Nuv) / (double)(Nuv - 1);
    float pad = (float)(0.9 / (double)Nuv);
    float val;
    if ((e & 1) == 0) {
        float tx = (j == Nuv - 1) ? (float)(1.0 - 1.0 / (double)Nuv)
                                  : (float)((double)j * step);
        val = (c == 1 || c == 2) ? tx + pad : tx;
    } else {
        float ty = (i == Nuv - 1) ? (float)(1.0 - 1.0 / (double)Nuv)
                                  : (float)((double)i * step);
        val = (c >= 2) ? ty + pad : ty;
    }
    uvs[(u64)i * (u64)rowElems + (u64)e] = val;
}

extern "C" void kernel_launch(void* const* d_in, const int* in_sizes, int n_in,
                              void* d_out, int out_size, void* d_ws, size_t ws_size,
                              hipStream_t stream) {
    const float* sdf = (const float*)d_in[1];
    int Nv = in_sizes[1];
    int F = in_sizes[2] / 4;

    int V = 1;
    while ((long long)V * V * V < (long long)Nv) V++;
    int G = V - 1;
    int nC = G * G * G;

    long long half = (2ll * (long long)F + 1) / 2;
    int Nuv = (int)std::sqrt((double)half);
    while ((long long)Nuv * Nuv < half) Nuv++;
    while (Nuv > 1 && (long long)(Nuv - 1) * (Nuv - 1) >= half) Nuv--;

    int nbV = (Nv + 255) / 256;
    int nbC = (nC + 255) / 256;
    int rowElems = 8 * Nuv;
    long long npts2 = 2ll * 4ll * (long long)Nuv * (long long)Nuv;

    char* ws = (char*)d_ws;
    size_t off = 0;
    auto walloc = [&](size_t bytes) -> void* {
        void* p = ws + off;
        off = (off + bytes + 255) & ~(size_t)255;
        return p;
    };
    u32* totals = (u32*)walloc(64);
    u32* vbsums = (u32*)walloc(sizeof(u32) * (size_t)nbV);
    u32* cbsums = (u32*)walloc(sizeof(u32) * (size_t)nbC);
    u64* coffs  = (u64*)walloc(sizeof(u64) * (size_t)nbC);
    u8*  vmask  = (u8*)walloc((size_t)Nv);
    u32* vbase  = (u32*)walloc(sizeof(u32) * (size_t)Nv);
    (void)ws_size;

    float* out = (float*)d_out;
    float h = 2.0f / (float)G;

    hipLaunchKernelGGL(k_vmask, dim3(nbV), dim3(256), 0, stream, sdf, vmask, vbsums, Nv, V);
    hipLaunchKernelGGL(k_cubecnt, dim3(nbC), dim3(256), 0, stream, vmask, cbsums, nC, G, V);
    hipLaunchKernelGGL(k_scan_both, dim3(2), dim3(1024), 0, stream, vbsums, nbV, cbsums, coffs,
                       nbC, totals);
    hipLaunchKernelGGL(k_vbase_verts, dim3(nbV), dim3(256), 0, stream, vmask, vbsums, vbase,
                       sdf, out, Nv, V, h);
    hipLaunchKernelGGL(k_facesuv, dim3(nbC), dim3(256), 0, stream, vmask, vbase, coffs, totals,
                       out, nC, G, V, npts2);
    hipLaunchKernelGGL(k_uvs, dim3((rowElems + 255) / 256, Nuv), dim3(256), 0, stream, out,
                       totals, Nuv, rowElems);
}

// Round 4
// 175.508 us; speedup vs baseline: 2.3144x; 1.6400x over previous
//
#include <hip/hip_runtime.h>
#include <cmath>

typedef unsigned int u32;
typedef unsigned long long u64;
typedef unsigned char u8;
typedef float f32x4 __attribute__((ext_vector_type(4)));

// Marching-tets tables from the reference
__constant__ signed char c_tri[16][6] = {
    {-1,-1,-1,-1,-1,-1},
    { 1, 0, 2,-1,-1,-1},
    { 4, 0, 3,-1,-1,-1},
    { 1, 4, 2, 1, 3, 4},
    { 3, 1, 5,-1,-1,-1},
    { 2, 3, 0, 2, 5, 3},
    { 1, 4, 0, 1, 5, 4},
    { 4, 2, 5,-1,-1,-1},
    { 4, 5, 2,-1,-1,-1},
    { 4, 1, 0, 4, 5, 1},
    { 3, 2, 0, 3, 5, 2},
    { 1, 3, 5,-1,-1,-1},
    { 4, 1, 2, 4, 3, 1},
    { 3, 0, 4,-1,-1,-1},
    { 2, 0, 1,-1,-1,-1},
    {-1,-1,-1,-1,-1,-1}};
__constant__ signed char c_ntri[16] = {0,1,1,2,1,2,2,1,1,2,2,1,2,1,1,0};
__constant__ signed char c_edge_p[6] = {0,0,0,1,1,2};
__constant__ signed char c_edge_q[6] = {1,2,3,2,3,3};
// 6-tet decomposition of a cube around the 0-7 diagonal (corner n: bit0=dx,bit1=dy,bit2=dz)
__constant__ u8 c_six[6][4] = {{0,5,1,7},{0,1,3,7},{0,3,2,7},{0,2,6,7},{0,6,4,7},{0,4,5,7}};

// ---- V-pass 1: crossing mask (bits 0..6) + occ (bit 7) + per-block counts --
__global__ void k_vmask(const float* __restrict__ sdf, u8* __restrict__ vmask,
                        u32* __restrict__ vbsums, int Nv, int V) {
    int v = blockIdx.x * 256 + threadIdx.x;
    u32 cnt = 0;
    if (v < Nv) {
        int x = v % V;
        int t = v / V;
        int y = t % V;
        int z = t / V;
        const int V2 = V * V;
        bool occ0 = sdf[v] > 0.0f;
        bool bx = x < V - 1, by = y < V - 1, bz = z < V - 1;
        int  d[7]  = {1, V, V + 1, V2, V2 + 1, V2 + V, V2 + V + 1};
        bool ok[7] = {bx, by, bx && by, bz, bx && bz, by && bz, bx && by && bz};
        u32 m = 0;
#pragma unroll
        for (int k = 0; k < 7; ++k) {
            if (ok[k]) {
                bool occ1 = sdf[v + d[k]] > 0.0f;
                if (occ1 != occ0) m |= (1u << k);
            }
        }
        vmask[v] = (u8)(m | (occ0 ? 0x80u : 0u));
        cnt = __popc(m);
    }
    int lane = threadIdx.x & 63, wid = threadIdx.x >> 6;
    u32 s = cnt;
#pragma unroll
    for (int o = 32; o > 0; o >>= 1) s += __shfl_down(s, o, 64);
    __shared__ u32 wsum[4];
    if (lane == 0) wsum[wid] = s;
    __syncthreads();
    if (threadIdx.x == 0) vbsums[blockIdx.x] = wsum[0] + wsum[1] + wsum[2] + wsum[3];
}

// ---- C-pass 1: per-cube (m1,m2) tet counts, per-block packed sums ----------
__global__ void k_cubecnt(const u8* __restrict__ vmask, u32* __restrict__ cbsums,
                          int nC, int G, int V) {
    int ci = blockIdx.x * 256 + threadIdx.x;
    u32 pack = 0;
    if (ci < nC) {
        int x = ci % G;
        int t = ci / G;
        int y = t % G;
        int z = t / G;
        const int V2 = V * V;
        int nb = z * V2 + y * V + x;
        const int off[8] = {0, 1, V, V + 1, V2, V2 + 1, V2 + V, V2 + V + 1};
        u32 occ8 = 0;
#pragma unroll
        for (int n = 0; n < 8; ++n) occ8 |= (u32)(vmask[nb + off[n]] >> 7) << n;
        u32 c1 = 0, c2 = 0;
#pragma unroll
        for (int w = 0; w < 6; ++w) {
            int ti = ((occ8 >> c_six[w][0]) & 1) | (((occ8 >> c_six[w][1]) & 1) << 1) |
                     (((occ8 >> c_six[w][2]) & 1) << 2) | (((occ8 >> c_six[w][3]) & 1) << 3);
            int nt = c_ntri[ti];
            c1 += (nt == 1);
            c2 += (nt == 2);
        }
        pack = c1 | (c2 << 16);
    }
    int lane = threadIdx.x & 63, wid = threadIdx.x >> 6;
    u32 s = pack;
#pragma unroll
    for (int o = 32; o > 0; o >>= 1) s += __shfl_down(s, o, 64);
    __shared__ u32 wsum[4];
    if (lane == 0) wsum[wid] = s;
    __syncthreads();
    if (threadIdx.x == 0) cbsums[blockIdx.x] = wsum[0] + wsum[1] + wsum[2] + wsum[3];
}

// ---- scans (block 0: u32 vbsums; block 1: packed->u64 cbsums->coffs) -------
__global__ void k_scan_both(u32* __restrict__ vbsums, int nV,
                            const u32* __restrict__ cbsums, u64* __restrict__ coffs,
                            int nC, u32* __restrict__ totals) {
    int tid = threadIdx.x;
    int lane = tid & 63, wid = tid >> 6;
    if (blockIdx.x == 0) {
        __shared__ u32 wsum[16];
        __shared__ u32 carry;
        if (tid == 0) carry = 0;
        __syncthreads();
        for (int start = 0; start < nV; start += 1024) {
            int i = start + tid;
            u32 orig = (i < nV) ? vbsums[i] : 0u;
            u32 v = orig;
#pragma unroll
            for (int o = 1; o < 64; o <<= 1) {
                u32 t = __shfl_up(v, o, 64);
                if (lane >= o) v += t;
            }
            if (lane == 63) wsum[wid] = v;
            __syncthreads();
            if (wid == 0) {
                u32 w = (lane < 16) ? wsum[lane] : 0u;
#pragma unroll
                for (int o = 1; o < 16; o <<= 1) {
                    u32 t = __shfl_up(w, o, 64);
                    if (lane >= o) w += t;
                }
                if (lane < 16) wsum[lane] = w;
            }
            __syncthreads();
            u32 base = carry + (wid ? wsum[wid - 1] : 0u);
            if (i < nV) vbsums[i] = base + v - orig;
            __syncthreads();
            if (tid == 0) carry += wsum[15];
            __syncthreads();
        }
        if (tid == 0) totals[0] = carry;  // E
    } else {
        __shared__ u64 wsum[16];
        __shared__ u64 carry;
        if (tid == 0) carry = 0;
        __syncthreads();
        for (int start = 0; start < nC; start += 1024) {
            int i = start + tid;
            u32 raw = (i < nC) ? cbsums[i] : 0u;
            u64 orig = (u64)(raw & 0xFFFFu) | ((u64)(raw >> 16) << 32);
            u64 v = orig;
#pragma unroll
            for (int o = 1; o < 64; o <<= 1) {
                u64 t = __shfl_up(v, o, 64);
                if (lane >= o) v += t;
            }
            if (lane == 63) wsum[wid] = v;
            __syncthreads();
            if (wid == 0) {
                u64 w = (lane < 16) ? wsum[lane] : 0ull;
#pragma unroll
                for (int o = 1; o < 16; o <<= 1) {
                    u64 t = __shfl_up(w, o, 64);
                    if (lane >= o) w += t;
                }
                if (lane < 16) wsum[lane] = w;
            }
            __syncthreads();
            u64 base = carry + (wid ? wsum[wid - 1] : 0ull);
            if (i < nC) coffs[i] = base + v - orig;
            __syncthreads();
            if (tid == 0) carry += wsum[15];
            __syncthreads();
        }
        if (tid == 0) {
            totals[1] = (u32)(carry & 0xFFFFFFFFull);  // Tm1
            totals[2] = (u32)(carry >> 32);            // Tm2
        }
    }
}

// ---- vbase materialize + crossing-vertex interpolation (fused) ------------
__global__ void k_vbase_verts(const u8* __restrict__ vmask, const u32* __restrict__ vbsums,
                              u32* __restrict__ vbase, const float* __restrict__ sdf,
                              float* __restrict__ out, int Nv, int V, float h) {
    int v = blockIdx.x * 256 + threadIdx.x;
    u32 m = (v < Nv) ? (u32)(vmask[v] & 0x7Fu) : 0u;
    u32 cnt = __popc(m);
    int lane = threadIdx.x & 63, wid = threadIdx.x >> 6;
    u32 s = cnt;
#pragma unroll
    for (int o = 1; o < 64; o <<= 1) {
        u32 t = __shfl_up(s, o, 64);
        if (lane >= o) s += t;
    }
    __shared__ u32 wsum[4];
    if (lane == 63) wsum[wid] = s;
    __syncthreads();
    u32 wb = 0;
    for (int k = 0; k < 4; ++k)
        if (k < wid) wb += wsum[k];
    u32 base = vbsums[blockIdx.x] + wb + s - cnt;
    if (v < Nv) vbase[v] = base;
    if (!m) return;

    int x = v % V;
    int t2 = v / V;
    int y = t2 % V;
    int z = t2 / V;
    const int V2 = V * V;
    const int d[7]  = {1, V, V + 1, V2, V2 + 1, V2 + V, V2 + V + 1};
    const int dx[7] = {1, 0, 1, 0, 1, 0, 1};
    const int dy[7] = {0, 1, 1, 0, 0, 1, 1};
    const int dz[7] = {0, 0, 0, 1, 1, 1, 1};
    float px = -1.0f + x * h, py = -1.0f + y * h, pz = -1.0f + z * h;
    float s0 = sdf[v];
    u32 r = base;
#pragma unroll
    for (int k = 0; k < 7; ++k) {
        if (m & (1u << k)) {
            float s1 = sdf[v + d[k]];
            float denom = s0 - s1;
            float w0 = -s1 / denom;
            float w1 = s0 / denom;
            out[3ull * r + 0] = px * w0 + (px + dx[k] * h) * w1;
            out[3ull * r + 1] = py * w0 + (py + dy[k] * h) * w1;
            out[3ull * r + 2] = pz * w0 + (pz + dz[k] * h) * w1;
            r++;
        }
    }
}

// ---- faces + uv_idx, per-cube, procedural connectivity --------------------
__global__ void k_facesuv(const u8* __restrict__ vmask, const u32* __restrict__ vbase,
                          const u64* __restrict__ coffs, const u32* __restrict__ totals,
                          float* __restrict__ out, int nC, int G, int V, long long npts2) {
    int ci = blockIdx.x * 256 + threadIdx.x;
    const int V2 = V * V;
    u32 pack = 0, occ8 = 0;
    int nb = 0;
    if (ci < nC) {
        int x = ci % G;
        int t = ci / G;
        int y = t % G;
        int z = t / G;
        nb = z * V2 + y * V + x;
        const int off[8] = {0, 1, V, V + 1, V2, V2 + 1, V2 + V, V2 + V + 1};
#pragma unroll
        for (int n = 0; n < 8; ++n) occ8 |= (u32)(vmask[nb + off[n]] >> 7) << n;
        u32 c1 = 0, c2 = 0;
#pragma unroll
        for (int w = 0; w < 6; ++w) {
            int ti = ((occ8 >> c_six[w][0]) & 1) | (((occ8 >> c_six[w][1]) & 1) << 1) |
                     (((occ8 >> c_six[w][2]) & 1) << 2) | (((occ8 >> c_six[w][3]) & 1) << 3);
            int nt = c_ntri[ti];
            c1 += (nt == 1);
            c2 += (nt == 2);
        }
        pack = c1 | (c2 << 16);
    }
    int lane = threadIdx.x & 63, wid = threadIdx.x >> 6;
    u32 s = pack;
#pragma unroll
    for (int o = 1; o < 64; o <<= 1) {
        u32 t = __shfl_up(s, o, 64);
        if (lane >= o) s += t;
    }
    __shared__ u32 wsum[4];
    if (lane == 63) wsum[wid] = s;
    __syncthreads();
    u32 wb = 0;
    for (int k = 0; k < 4; ++k)
        if (k < wid) wb += wsum[k];
    u32 excl = wb + s - pack;
    if (ci >= nC || pack == 0) return;

    u64 bo = coffs[blockIdx.x];
    u32 m1pos = (u32)(bo & 0xFFFFFFFFull) + (excl & 0xFFFFu);
    u32 m2pos = (u32)(bo >> 32) + (excl >> 16);
    u32 E = totals[0], Tm1 = totals[1], Tm2 = totals[2];
    u64 T = (u64)Tm1 + 2ull * (u64)Tm2;
    float* faces = out + 3ull * E;
    float* uvidx = out + 3ull * E + 3ull * T + (u64)npts2;
    const int off[8] = {0, 1, V, V + 1, V2, V2 + 1, V2 + V, V2 + V + 1};

#pragma unroll
    for (int w = 0; w < 6; ++w) {
        int ti = ((occ8 >> c_six[w][0]) & 1) | (((occ8 >> c_six[w][1]) & 1) << 1) |
                 (((occ8 >> c_six[w][2]) & 1) << 2) | (((occ8 >> c_six[w][3]) & 1) << 3);
        int nt = c_ntri[ti];
        if (!nt) continue;
        int t = ci * 6 + w;
        for (int tri = 0; tri < nt; ++tri) {
            u64 r = (nt == 1) ? (u64)m1pos : ((u64)Tm1 + 2ull * (u64)m2pos + (u64)tri);
#pragma unroll
            for (int cidx = 0; cidx < 3; ++cidx) {
                int e = c_tri[ti][3 * tri + cidx];
                int np_ = c_six[w][(int)c_edge_p[e]];
                int nq_ = c_six[w][(int)c_edge_q[e]];
                int lo = np_ < nq_ ? np_ : nq_;
                int k = (np_ ^ nq_) - 1;  // corners form a bit-subset chain
                int lonode = nb + off[lo];
                u32 vi = vbase[lonode] +
                         (u32)__popc((u32)(vmask[lonode] & 0x7Fu) & ((1u << k) - 1u));
                faces[3ull * r + cidx] = (float)vi;
            }
            uvidx[3ull * r + 0] = (float)(4 * t);
            uvidx[3ull * r + 1] = (float)(4 * t + tri + 1);
            uvidx[3ull * r + 2] = (float)(4 * t + tri + 2);
        }
        if (nt == 1) m1pos++;
        else m2pos++;
    }
}

// ---- uvs helpers -----------------------------------------------------------
__device__ inline float uv_elem(long long e, int Nuv, double invN, double step_d,
                                float pad, float last) {
    int p = (int)(e >> 3);
    int i = (int)((double)p * invN);
    int j = p - i * Nuv;
    if (j >= Nuv) { j -= Nuv; ++i; }
    int r = (int)(e & 7);
    int c = r >> 1;
    if ((r & 1) == 0) {
        float tx = (j == Nuv - 1) ? last : (float)((double)j * step_d);
        return tx + ((c == 1 || c == 2) ? pad : 0.0f);
    }
    float ty = (i == Nuv - 1) ? last : (float)((double)i * step_d);
    return ty + ((c >= 2) ? pad : 0.0f);
}

// ---- uvs: static texture grid; one 16B store / thread, host constants -----
__global__ void k_uvs(float* __restrict__ out, const u32* __restrict__ totals,
                      int Nuv, double invN, double step_d, float pad, float last,
                      long long npts2) {
    u32 E = totals[0], Tm1 = totals[1], Tm2 = totals[2];
    u64 base = 3ull * E + 3ull * ((u64)Tm1 + 2ull * (u64)Tm2);
    float* uvs = out + base;
    long long head = (long long)((4 - (base & 3)) & 3);
    long long nvec = (npts2 - head) >> 2;  // full 16B stores
    long long t = (long long)blockIdx.x * 256 + threadIdx.x;
    if (t < nvec) {
        long long e0 = head + 4 * t;
        int p = (int)(e0 >> 3);
        int i = (int)((double)p * invN);
        int j = p - i * Nuv;
        if (j >= Nuv) { j -= Nuv; ++i; }
        float tx = (j == Nuv - 1) ? last : (float)((double)j * step_d);
        float ty = (i == Nuv - 1) ? last : (float)((double)i * step_d);
        f32x4 vals;
        int pcur = p;
#pragma unroll
        for (int q = 0; q < 4; ++q) {
            long long e = e0 + q;
            int pe = (int)(e >> 3);
            if (pe != pcur) {
                pcur = pe;
                ++j;
                if (j == Nuv) {
                    j = 0;
                    ++i;
                    ty = (i == Nuv - 1) ? last : (float)((double)i * step_d);
                }
                tx = (j == Nuv - 1) ? last : (float)((double)j * step_d);
            }
            int r = (int)(e & 7);
            int c = r >> 1;
            float v;
            if ((r & 1) == 0) v = tx + ((c == 1 || c == 2) ? pad : 0.0f);
            else              v = ty + ((c >= 2) ? pad : 0.0f);
            vals[q] = v;
        }
        __builtin_nontemporal_store(vals, (f32x4*)(uvs + e0));
    } else if (t == nvec) {
        for (long long e = 0; e < head; ++e)
            uvs[e] = uv_elem(e, Nuv, invN, step_d, pad, last);
        for (long long e = head + 4 * nvec; e < npts2; ++e)
            uvs[e] = uv_elem(e, Nuv, invN, step_d, pad, last);
    }
}

extern "C" void kernel_launch(void* const* d_in, const int* in_sizes, int n_in,
                              void* d_out, int out_size, void* d_ws, size_t ws_size,
                              hipStream_t stream) {
    const float* sdf = (const float*)d_in[1];
    int Nv = in_sizes[1];
    int F = in_sizes[2] / 4;

    int V = 1;
    while ((long long)V * V * V < (long long)Nv) V++;
    int G = V - 1;
    int nC = G * G * G;

    long long half = (2ll * (long long)F + 1) / 2;
    int Nuv = (int)std::sqrt((double)half);
    while ((long long)Nuv * Nuv < half) Nuv++;
    while (Nuv > 1 && (long long)(Nuv - 1) * (Nuv - 1) >= half) Nuv--;

    int nbV = (Nv + 255) / 256;
    int nbC = (nC + 255) / 256;
    long long npts2 = 2ll * 4ll * (long long)Nuv * (long long)Nuv;

    double invN = 1.0 / (double)Nuv;
    double step_d = (1.0 - invN) / (double)(Nuv - 1);
    float pad = (float)(0.9 * invN);
    float last = (float)(1.0 - invN);

    char* ws = (char*)d_ws;
    size_t off = 0;
    auto walloc = [&](size_t bytes) -> void* {
        void* p = ws + off;
        off = (off + bytes + 255) & ~(size_t)255;
        return p;
    };
    u32* totals = (u32*)walloc(64);
    u32* vbsums = (u32*)walloc(sizeof(u32) * (size_t)nbV);
    u32* cbsums = (u32*)walloc(sizeof(u32) * (size_t)nbC);
    u64* coffs  = (u64*)walloc(sizeof(u64) * (size_t)nbC);
    u8*  vmask  = (u8*)walloc((size_t)Nv);
    u32* vbase  = (u32*)walloc(sizeof(u32) * (size_t)Nv);
    (void)ws_size;

    float* out = (float*)d_out;
    float h = 2.0f / (float)G;

    long long nthr_uvs = npts2 / 4 + 1;
    int nbU = (int)((nthr_uvs + 255) / 256);

    hipLaunchKernelGGL(k_vmask, dim3(nbV), dim3(256), 0, stream, sdf, vmask, vbsums, Nv, V);
    hipLaunchKernelGGL(k_cubecnt, dim3(nbC), dim3(256), 0, stream, vmask, cbsums, nC, G, V);
    hipLaunchKernelGGL(k_scan_both, dim3(2), dim3(1024), 0, stream, vbsums, nbV, cbsums, coffs,
                       nbC, totals);
    hipLaunchKernelGGL(k_vbase_verts, dim3(nbV), dim3(256), 0, stream, vmask, vbsums, vbase,
                       sdf, out, Nv, V, h);
    hipLaunchKernelGGL(k_facesuv, dim3(nbC), dim3(256), 0, stream, vmask, vbase, coffs, totals,
                       out, nC, G, V, npts2);
    hipLaunchKernelGGL(k_uvs, dim3(nbU), dim3(256), 0, stream, out, totals, Nuv, invN, step_d,
                       pad, last, npts2);
}